// Round 10
// baseline (18141.121 us; speedup 1.0000x reference)
//
#include <hip/hip_runtime.h>
#include <math.h>

// TD3ActorDSNN — f32 class-faithful, fused, round 10.
// Exactness invariants (validated r4-r6, r9):
//  - per-element k-ascending single-accumulator f32 chains for h0 and h1;
//    skipping zero terms is bit-identical; add order never changes.
//  - b in {0,1}: b*w is EXACT (0 or w), so mul+add == fma == conditional add,
//    all bit-identical. v_pk_fma_f32 = two independent IEEE fmas -> exact.
//  - recurrences: __fadd_rn(__fmul_rn(beta,state),h) (np mul-then-add).
//  - layer2/mem2: order-free (tanh input, tol 2e-2 >> 1e-6 noise).
// r7/r8 lesson: multi-way branches / asm operands on the 60 live accs =>
// scratch spills (WRITE_SIZE 16MB->10GB). Keep ONE uniform guard +
// straight-line body. r9 lesson (counters): f32x2 arith got scalarized
// (52 VALU/k) and launch_bounds(,4) capped occupancy at 54%.
// Round-10 changes ONLY:
//  - __launch_bounds__(256, 8): 8 waves/SIMD (VGPR 44 fits under the 64 cap).
//  - __builtin_elementwise_fma on float2 to force v_pk_fma_f32 selection.

typedef unsigned int u32;
typedef unsigned short u16;
typedef __attribute__((ext_vector_type(2))) float f32x2;

// ---- K1: h0 = inputs @ W0 (f32 fma chain) + fused mem0 recurrence -> s0bR ----
__global__ __launch_bounds__(256) void h0_kernel(
    const float* __restrict__ in, const float* __restrict__ W0,
    u16* __restrict__ s0bR) {
    __shared__ float Ls[32 * 512];
    int tid = threadIdx.x;
    int j = blockIdx.x * 256 + tid;
    int r0 = blockIdx.y * 32;
#pragma unroll
    for (int i = 0; i < 64; ++i) {
        int e = i * 256 + tid;
        Ls[e] = in[(size_t)(r0 + (e >> 9)) * 512 + (e & 511)];
    }
    __syncthreads();
    float acc[32];
#pragma unroll
    for (int r = 0; r < 32; ++r) acc[r] = 0.f;
    for (int k = 0; k < 512; ++k) {
        float w = W0[(size_t)k * 2048 + j];
#pragma unroll
        for (int r = 0; r < 32; ++r)
            acc[r] = __fmaf_rn(Ls[r * 512 + k], w, acc[r]);
    }
#pragma unroll
    for (int r = 0; r < 32; ++r) {
        float h = acc[r], mem = 0.f;
        u32 bits = 0;
#pragma unroll
        for (int t = 0; t < 15; ++t) {
            float nm = __fadd_rn(__fmul_rn(0.85f, mem), h);  // np: mul, then add
            bool sp = nm > 1.0f;
            bits |= (sp ? 1u : 0u) << t;
            mem = sp ? 0.f : nm;
        }
        s0bR[(size_t)(r0 + r) * 2048 + j] = (u16)bits;
    }
}

// ---- K2: FUSED h1 (15 steps) + in-register syn1/mem1 recurrence -> s1b ----
// Wave: 1 row x 256 cols (lane: 4 cols via float4 -> 2x f32x2). Block: 4 rows.
// grid 8192: jb = id&7 (XCD-affine W1 slice), rblk = id>>3.
__global__ __launch_bounds__(256, 8) void h1_fused6(
    const float* __restrict__ W1, const u16* __restrict__ s0bR,
    u16* __restrict__ s1b) {
    int id = blockIdx.x;
    int jb = id & 7, rblk = id >> 3;
    int lane = threadIdx.x & 63, wv = threadIdx.x >> 6;
    int row = rblk * 4 + wv;
    int j0 = jb * 256 + lane * 4;
    const float* wp = W1 + j0;
    const u16* mp = s0bR + (size_t)row * 2048;

    f32x2 acc[15][2];
#pragma unroll
    for (int t = 0; t < 15; ++t) {
        acc[t][0] = (f32x2){0.f, 0.f};
        acc[t][1] = (f32x2){0.f, 0.f};
    }

    float4 wc = *(const float4*)(wp);       // w for k=0
    uint4 m8 = *(const uint4*)(mp);         // masks k=0..7
    for (int kb = 0; kb < 2048; kb += 8) {
        // lookahead (last group overruns into s1b region; values unused)
        uint4 m8n = *(const uint4*)(mp + kb + 8);
#pragma unroll
        for (int kk = 0; kk < 8; ++kk) {
            int k = kb + kk;
            float4 wcur = wc;
            // prefetch next k's w (guard last k; uniform select)
            wc = *(const float4*)(wp + (size_t)(k < 2047 ? k + 1 : k) * 2048);
            u32 word = (kk < 2) ? m8.x : (kk < 4) ? m8.y : (kk < 6) ? m8.z : m8.w;
            u32 mask = __builtin_amdgcn_readfirstlane(
                           (kk & 1) ? (word >> 16) : word) & 0x7FFFu;
            if (mask) {                      // single uniform guard (~44% taken)
                f32x2 w01 = {wcur.x, wcur.y};
                f32x2 w23 = {wcur.z, wcur.w};
#pragma unroll
                for (int t = 0; t < 15; ++t) {
                    float b = (mask & (1u << t)) ? 1.0f : 0.0f;
                    f32x2 b2 = {b, b};
                    // explicit vector fma -> v_pk_fma_f32; exact since b in {0,1}
                    acc[t][0] = __builtin_elementwise_fma(b2, w01, acc[t][0]);
                    acc[t][1] = __builtin_elementwise_fma(b2, w23, acc[t][1]);
                }
            }
        }
        m8 = m8n;
    }

    // layer-1 recurrence per element (np rounding order) -> s1 bitmasks
    u16 ob[4];
#pragma unroll
    for (int q = 0; q < 4; ++q) {
        float syn = 0.f, mem = 0.f;
        u32 obits = 0;
#pragma unroll
        for (int t = 0; t < 15; ++t) {
            float h1 = acc[t][q >> 1][q & 1];   // static indices after unroll
            float ns = __fadd_rn(__fmul_rn(0.9f, syn), h1);
            float nm = __fadd_rn(__fmul_rn(0.85f, mem), ns);
            bool sp = nm > 1.0f;
            obits |= (sp ? 1u : 0u) << t;
            syn = ns;
            mem = sp ? 0.f : nm;
        }
        ob[q] = (u16)obits;
    }
    uint2 pk;
    pk.x = (u32)ob[0] | ((u32)ob[1] << 16);
    pk.y = (u32)ob[2] | ((u32)ob[3] << 16);
    *(uint2*)(s1b + (size_t)row * 2048 + j0) = pk;
}

// ---- K3: out = tanh(sum_t s1_t @ W2) (order-free reduction) ----
__global__ __launch_bounds__(256) void out_kernel(
    const u16* __restrict__ s1b, const float* __restrict__ W2,
    float* __restrict__ out) {
    __shared__ float P[4][15][8];
    int row = blockIdx.x;
    int tid = threadIdx.x, lane = tid & 63, wv = tid >> 6;
    const u16* srow = s1b + (size_t)row * 2048;
    union { uint4 v; u16 m[8]; } u;
    u.v = *(const uint4*)(srow + tid * 8);
#pragma unroll
    for (int t = 0; t < 15; ++t) {
        float a[8];
#pragma unroll
        for (int jj = 0; jj < 8; ++jj) a[jj] = 0.f;
#pragma unroll
        for (int kk = 0; kk < 8; ++kk) {
            const float* wr = W2 + (size_t)(tid * 8 + kk) * 8;
            if ((u.m[kk] >> t) & 1u) {
#pragma unroll
                for (int jj = 0; jj < 8; ++jj)
                    a[jj] = __fadd_rn(a[jj], wr[jj]);
            }
        }
#pragma unroll
        for (int jj = 0; jj < 8; ++jj) {
            float v = a[jj];
#pragma unroll
            for (int m = 1; m < 64; m <<= 1) v += __shfl_xor(v, m, 64);
            a[jj] = v;
        }
        if (lane == 0) {
#pragma unroll
            for (int jj = 0; jj < 8; ++jj) P[wv][t][jj] = a[jj];
        }
    }
    __syncthreads();
    if (tid < 8) {
        float m2 = 0.f;
#pragma unroll
        for (int t = 0; t < 15; ++t) {
            float s = __fadd_rn(__fadd_rn(P[0][t][tid], P[1][t][tid]),
                                __fadd_rn(P[2][t][tid], P[3][t][tid]));
            m2 = __fadd_rn(m2, s);
        }
        out[(size_t)row * 8 + tid] = tanhf(m2);
    }
}

extern "C" void kernel_launch(void* const* d_in, const int* in_sizes, int n_in,
                              void* d_out, int out_size, void* d_ws, size_t ws_size,
                              hipStream_t stream) {
    const float* inp = (const float*)d_in[0];
    const float* W0  = (const float*)d_in[1];
    const float* W1  = (const float*)d_in[2];
    const float* W2  = (const float*)d_in[3];
    float* out = (float*)d_out;
    char* ws = (char*)d_ws;

    u16* s0bR = (u16*)(ws + 0);           // 16,777,216  [row][k] 15-bit masks
    u16* s1b  = (u16*)(ws + 16777216);    // 16,777,216  [row][j] 15-bit masks
    if (ws_size < 33554432) return;       // 32 MB scratch

    h0_kernel<<<dim3(8, 128), 256, 0, stream>>>(inp, W0, s0bR);
    h1_fused6<<<8192, 256, 0, stream>>>(W1, s0bR, s1b);
    out_kernel<<<4096, 256, 0, stream>>>(s1b, W2, out);
}

// Round 11
// 3487.038 us; speedup vs baseline: 5.2024x; 5.2024x over previous
//
#include <hip/hip_runtime.h>
#include <math.h>

// TD3ActorDSNN — f32 class-faithful, fused, round 11.
// Exactness invariants (validated r4-r6, r9):
//  - per-element k-ascending single-accumulator f32 chains for h0 and h1;
//    skipping k with mask==0 is bit-identical (contributes no add to any t);
//    entries with mask==0 are exact no-ops (b=0 -> fma(0,w,acc)==acc).
//  - b in {0,1}: b*w exact -> mul+add == fma == conditional add, bit-identical.
//  - recurrences: __fadd_rn(__fmul_rn(beta,state),h) (np mul-then-add).
//  - layer2/mem2: order-free (tanh input, tol 2e-2 >> 1e-6 noise).
// Codegen lessons:
//  r7/r8: multi-way branches/asm on the 60 live accs => scratch spills
//         (WRITE_SIZE 16MB->10GB). Keep the hot body single-BB straight-line.
//  r10:   launch_bounds(256,8) => 32-VGPR cap => total spill (FETCH 1.5GB,
//         VALUBusy 14%). The 60-acc working set needs the (256,4) regime.
// Round-11 change: per-row compacted active-k list (k-ascending, built by
// ballot-prefix compaction, padded to x4 with mask=0 no-op entries). h1 loop
// visits ONLY active k (~44%) -> the ~19 VALU/k fixed overhead on inactive k
// disappears. Body identical to r9. No guard branch at all in the loop.

typedef unsigned int u32;
typedef unsigned short u16;
typedef unsigned long long u64;
typedef __attribute__((ext_vector_type(2))) float f32x2;

// ---- K1: h0 = inputs @ W0 (f32 fma chain) + fused mem0 recurrence -> s0bR ----
__global__ __launch_bounds__(256) void h0_kernel(
    const float* __restrict__ in, const float* __restrict__ W0,
    u16* __restrict__ s0bR) {
    __shared__ float Ls[32 * 512];
    int tid = threadIdx.x;
    int j = blockIdx.x * 256 + tid;
    int r0 = blockIdx.y * 32;
#pragma unroll
    for (int i = 0; i < 64; ++i) {
        int e = i * 256 + tid;
        Ls[e] = in[(size_t)(r0 + (e >> 9)) * 512 + (e & 511)];
    }
    __syncthreads();
    float acc[32];
#pragma unroll
    for (int r = 0; r < 32; ++r) acc[r] = 0.f;
    for (int k = 0; k < 512; ++k) {
        float w = W0[(size_t)k * 2048 + j];
#pragma unroll
        for (int r = 0; r < 32; ++r)
            acc[r] = __fmaf_rn(Ls[r * 512 + k], w, acc[r]);
    }
#pragma unroll
    for (int r = 0; r < 32; ++r) {
        float h = acc[r], mem = 0.f;
        u32 bits = 0;
#pragma unroll
        for (int t = 0; t < 15; ++t) {
            float nm = __fadd_rn(__fmul_rn(0.85f, mem), h);  // np: mul, then add
            bool sp = nm > 1.0f;
            bits |= (sp ? 1u : 0u) << t;
            mem = sp ? 0.f : nm;
        }
        s0bR[(size_t)(r0 + r) * 2048 + j] = (u16)bits;
    }
}

// ---- K1b: per-row active-k compaction (k-ascending preserved) ----
// wave per row; 32 chunks of 64 k; ballot + prefix -> packed (k<<16|mask).
__global__ __launch_bounds__(256) void compact_kernel(
    const u16* __restrict__ s0bR, u32* __restrict__ list,
    int* __restrict__ ccnt) {
    int wv = threadIdx.x >> 6, lane = threadIdx.x & 63;
    int row = blockIdx.x * 4 + wv;
    const u16* mrow = s0bR + (size_t)row * 2048;
    u32* lrow = list + (size_t)row * 2048;
    int base = 0;
    for (int c = 0; c < 32; ++c) {
        int k = c * 64 + lane;
        u32 m = mrow[k];
        bool act = m != 0u;
        u64 b = __ballot(act ? 1 : 0);
        int pre = __popcll(b & ((1ull << lane) - 1ull));
        if (act) lrow[base + pre] = ((u32)k << 16) | m;
        base += __popcll(b);
    }
    int padded = (base + 3) & ~3;
    if (lane < (padded - base)) lrow[base + lane] = 0u;   // mask=0 -> no-op
    if (lane == 0) ccnt[row] = padded;
}

// ---- K2: FUSED h1 (15 steps) over ACTIVE k only + recurrence -> s1b ----
// Wave: 1 row x 256 cols (lane: 4 cols). Block: 4 rows. grid 8192:
// jb = id&7 (XCD-affine W1 slice), rblk = id>>3. Straight-line body (r9's).
__global__ __launch_bounds__(256, 4) void h1_fused7(
    const float* __restrict__ W1, const u32* __restrict__ list,
    const int* __restrict__ ccnt, u16* __restrict__ s1b) {
    int id = blockIdx.x;
    int jb = id & 7, rblk = id >> 3;
    int lane = threadIdx.x & 63, wv = threadIdx.x >> 6;
    int row = rblk * 4 + wv;
    int j0 = jb * 256 + lane * 4;
    const float* wp = W1 + j0;
    const u32* lp = list + (size_t)row * 2048;
    int cnt = ccnt[row];                      // padded to multiple of 4

    f32x2 acc[15][2];
#pragma unroll
    for (int t = 0; t < 15; ++t) {
        acc[t][0] = (f32x2){0.f, 0.f};
        acc[t][1] = (f32x2){0.f, 0.f};
    }

#define BODY(E, W) {                                                  \
        u32 mask_ = __builtin_amdgcn_readfirstlane(E) & 0x7FFFu;      \
        f32x2 w01_ = {W.x, W.y}, w23_ = {W.z, W.w};                   \
        _Pragma("unroll")                                             \
        for (int t = 0; t < 15; ++t) {                                \
            float b_ = (mask_ & (1u << t)) ? 1.0f : 0.0f;             \
            f32x2 b2_ = {b_, b_};                                     \
            acc[t][0] = b2_ * w01_ + acc[t][0];                       \
            acc[t][1] = b2_ * w23_ + acc[t][1];                       \
        }                                                             \
    }

    for (int i = 0; i < cnt; i += 4) {
        uint4 e = *(const uint4*)(lp + i);    // 4 entries, uniform addr
        // issue the 4 w loads up front (independent; latency overlapped)
        float4 w0 = *(const float4*)(wp + ((size_t)(e.x >> 16) << 11));
        float4 w1 = *(const float4*)(wp + ((size_t)(e.y >> 16) << 11));
        float4 w2 = *(const float4*)(wp + ((size_t)(e.z >> 16) << 11));
        float4 w3 = *(const float4*)(wp + ((size_t)(e.w >> 16) << 11));
        BODY(e.x, w0);
        BODY(e.y, w1);
        BODY(e.z, w2);
        BODY(e.w, w3);
    }
#undef BODY

    // layer-1 recurrence per element (np rounding order) -> s1 bitmasks
    u16 ob[4];
#pragma unroll
    for (int q = 0; q < 4; ++q) {
        float syn = 0.f, mem = 0.f;
        u32 obits = 0;
#pragma unroll
        for (int t = 0; t < 15; ++t) {
            float h1 = acc[t][q >> 1][q & 1];   // static indices after unroll
            float ns = __fadd_rn(__fmul_rn(0.9f, syn), h1);
            float nm = __fadd_rn(__fmul_rn(0.85f, mem), ns);
            bool sp = nm > 1.0f;
            obits |= (sp ? 1u : 0u) << t;
            syn = ns;
            mem = sp ? 0.f : nm;
        }
        ob[q] = (u16)obits;
    }
    uint2 pk;
    pk.x = (u32)ob[0] | ((u32)ob[1] << 16);
    pk.y = (u32)ob[2] | ((u32)ob[3] << 16);
    *(uint2*)(s1b + (size_t)row * 2048 + j0) = pk;
}

// ---- K3: out = tanh(sum_t s1_t @ W2) (order-free reduction) ----
__global__ __launch_bounds__(256) void out_kernel(
    const u16* __restrict__ s1b, const float* __restrict__ W2,
    float* __restrict__ out) {
    __shared__ float P[4][15][8];
    int row = blockIdx.x;
    int tid = threadIdx.x, lane = tid & 63, wv = tid >> 6;
    const u16* srow = s1b + (size_t)row * 2048;
    union { uint4 v; u16 m[8]; } u;
    u.v = *(const uint4*)(srow + tid * 8);
#pragma unroll
    for (int t = 0; t < 15; ++t) {
        float a[8];
#pragma unroll
        for (int jj = 0; jj < 8; ++jj) a[jj] = 0.f;
#pragma unroll
        for (int kk = 0; kk < 8; ++kk) {
            const float* wr = W2 + (size_t)(tid * 8 + kk) * 8;
            if ((u.m[kk] >> t) & 1u) {
#pragma unroll
                for (int jj = 0; jj < 8; ++jj)
                    a[jj] = __fadd_rn(a[jj], wr[jj]);
            }
        }
#pragma unroll
        for (int jj = 0; jj < 8; ++jj) {
            float v = a[jj];
#pragma unroll
            for (int m = 1; m < 64; m <<= 1) v += __shfl_xor(v, m, 64);
            a[jj] = v;
        }
        if (lane == 0) {
#pragma unroll
            for (int jj = 0; jj < 8; ++jj) P[wv][t][jj] = a[jj];
        }
    }
    __syncthreads();
    if (tid < 8) {
        float m2 = 0.f;
#pragma unroll
        for (int t = 0; t < 15; ++t) {
            float s = __fadd_rn(__fadd_rn(P[0][t][tid], P[1][t][tid]),
                                __fadd_rn(P[2][t][tid], P[3][t][tid]));
            m2 = __fadd_rn(m2, s);
        }
        out[(size_t)row * 8 + tid] = tanhf(m2);
    }
}

extern "C" void kernel_launch(void* const* d_in, const int* in_sizes, int n_in,
                              void* d_out, int out_size, void* d_ws, size_t ws_size,
                              hipStream_t stream) {
    const float* inp = (const float*)d_in[0];
    const float* W0  = (const float*)d_in[1];
    const float* W1  = (const float*)d_in[2];
    const float* W2  = (const float*)d_in[3];
    float* out = (float*)d_out;
    char* ws = (char*)d_ws;

    u16* s0bR = (u16*)(ws + 0);            // 16,777,216  [row][k] 15-bit masks
    u16* s1b  = (u16*)(ws + 16777216);     // 16,777,216  [row][j] 15-bit masks
    u32* list = (u32*)(ws + 33554432);     // 33,554,432  [row][2048] (k<<16|mask)
    int* ccnt = (int*)(ws + 67108864);     //     16,384  padded counts
    if (ws_size < 67125248) return;        // ~64 MB scratch

    h0_kernel<<<dim3(8, 128), 256, 0, stream>>>(inp, W0, s0bR);
    compact_kernel<<<1024, 256, 0, stream>>>(s0bR, list, ccnt);
    h1_fused7<<<8192, 256, 0, stream>>>(W1, list, ccnt, s1b);
    out_kernel<<<4096, 256, 0, stream>>>(s1b, W2, out);
}

// Round 12
// 3408.629 us; speedup vs baseline: 5.3221x; 1.0230x over previous
//
#include <hip/hip_runtime.h>
#include <math.h>

// TD3ActorDSNN — f32 class-faithful, fused, round 12.
// Exactness invariants (validated r4-r6, r9, r11):
//  - per-element k-ascending single-accumulator f32 chains for h0 and h1;
//    skipping k with mask==0 is bit-identical; order never changes.
//  - b in {0,1}: fma(b,w,acc) is EXACT (b=1 -> RN(acc+w) == validated add;
//    b=0 -> acc unchanged; -0 unreachable from +0-init add chains).
//  - recurrences: __fadd_rn(__fmul_rn(beta,state),h) (np mul-then-add).
//  - layer2/mem2: order-free (tanh input, tol 2e-2 >> 1e-6 noise).
// Codegen lessons:
//  r7/r8: multi-way branches/asm on the 60 live accs => scratch spills.
//         Keep the hot body single-BB straight-line.
//  r10:   launch_bounds(256,8) => 32-VGPR cap => total spill. Need (256,4).
//  r9/r11: `b2*w + acc` emitted UNFUSED scalar mul+add (~120 VALU/entry,
//         106K issues/wave both rounds). Iteration count was never the lever.
// Round-12 change (only): __builtin_elementwise_fma on float2 — guaranteed
// fma (halves body) and the LLVM pattern that selects v_pk_fma_f32 (quarters).

typedef unsigned int u32;
typedef unsigned short u16;
typedef unsigned long long u64;
typedef __attribute__((ext_vector_type(2))) float f32x2;

// ---- K1: h0 = inputs @ W0 (f32 fma chain) + fused mem0 recurrence -> s0bR ----
__global__ __launch_bounds__(256) void h0_kernel(
    const float* __restrict__ in, const float* __restrict__ W0,
    u16* __restrict__ s0bR) {
    __shared__ float Ls[32 * 512];
    int tid = threadIdx.x;
    int j = blockIdx.x * 256 + tid;
    int r0 = blockIdx.y * 32;
#pragma unroll
    for (int i = 0; i < 64; ++i) {
        int e = i * 256 + tid;
        Ls[e] = in[(size_t)(r0 + (e >> 9)) * 512 + (e & 511)];
    }
    __syncthreads();
    float acc[32];
#pragma unroll
    for (int r = 0; r < 32; ++r) acc[r] = 0.f;
    for (int k = 0; k < 512; ++k) {
        float w = W0[(size_t)k * 2048 + j];
#pragma unroll
        for (int r = 0; r < 32; ++r)
            acc[r] = __fmaf_rn(Ls[r * 512 + k], w, acc[r]);
    }
#pragma unroll
    for (int r = 0; r < 32; ++r) {
        float h = acc[r], mem = 0.f;
        u32 bits = 0;
#pragma unroll
        for (int t = 0; t < 15; ++t) {
            float nm = __fadd_rn(__fmul_rn(0.85f, mem), h);  // np: mul, then add
            bool sp = nm > 1.0f;
            bits |= (sp ? 1u : 0u) << t;
            mem = sp ? 0.f : nm;
        }
        s0bR[(size_t)(r0 + r) * 2048 + j] = (u16)bits;
    }
}

// ---- K1b: per-row active-k compaction (k-ascending preserved) ----
__global__ __launch_bounds__(256) void compact_kernel(
    const u16* __restrict__ s0bR, u32* __restrict__ list,
    int* __restrict__ ccnt) {
    int wv = threadIdx.x >> 6, lane = threadIdx.x & 63;
    int row = blockIdx.x * 4 + wv;
    const u16* mrow = s0bR + (size_t)row * 2048;
    u32* lrow = list + (size_t)row * 2048;
    int base = 0;
    for (int c = 0; c < 32; ++c) {
        int k = c * 64 + lane;
        u32 m = mrow[k];
        bool act = m != 0u;
        u64 b = __ballot(act ? 1 : 0);
        int pre = __popcll(b & ((1ull << lane) - 1ull));
        if (act) lrow[base + pre] = ((u32)k << 16) | m;
        base += __popcll(b);
    }
    int padded = (base + 3) & ~3;
    if (lane < (padded - base)) lrow[base + lane] = 0u;   // mask=0 -> no-op
    if (lane == 0) ccnt[row] = padded;
}

// ---- K2: FUSED h1 (15 steps) over ACTIVE k only + recurrence -> s1b ----
// Wave: 1 row x 256 cols (lane: 4 cols). Block: 4 rows. grid 8192:
// jb = id&7 (XCD-affine W1 slice), rblk = id>>3. Single-BB body.
__global__ __launch_bounds__(256, 4) void h1_fused8(
    const float* __restrict__ W1, const u32* __restrict__ list,
    const int* __restrict__ ccnt, u16* __restrict__ s1b) {
    int id = blockIdx.x;
    int jb = id & 7, rblk = id >> 3;
    int lane = threadIdx.x & 63, wv = threadIdx.x >> 6;
    int row = rblk * 4 + wv;
    int j0 = jb * 256 + lane * 4;
    const float* wp = W1 + j0;
    const u32* lp = list + (size_t)row * 2048;
    int cnt = ccnt[row];                      // padded to multiple of 4

    f32x2 acc[15][2];
#pragma unroll
    for (int t = 0; t < 15; ++t) {
        acc[t][0] = (f32x2){0.f, 0.f};
        acc[t][1] = (f32x2){0.f, 0.f};
    }

#define BODY(E, W) {                                                  \
        u32 mask_ = __builtin_amdgcn_readfirstlane(E) & 0x7FFFu;      \
        f32x2 w01_ = {W.x, W.y}, w23_ = {W.z, W.w};                   \
        _Pragma("unroll")                                             \
        for (int t = 0; t < 15; ++t) {                                \
            float b_ = (mask_ & (1u << t)) ? 1.0f : 0.0f;             \
            f32x2 b2_ = {b_, b_};                                     \
            acc[t][0] = __builtin_elementwise_fma(b2_, w01_, acc[t][0]); \
            acc[t][1] = __builtin_elementwise_fma(b2_, w23_, acc[t][1]); \
        }                                                             \
    }

    for (int i = 0; i < cnt; i += 4) {
        uint4 e = *(const uint4*)(lp + i);    // 4 entries, uniform addr
        float4 w0 = *(const float4*)(wp + ((size_t)(e.x >> 16) << 11));
        float4 w1 = *(const float4*)(wp + ((size_t)(e.y >> 16) << 11));
        float4 w2 = *(const float4*)(wp + ((size_t)(e.z >> 16) << 11));
        float4 w3 = *(const float4*)(wp + ((size_t)(e.w >> 16) << 11));
        BODY(e.x, w0);
        BODY(e.y, w1);
        BODY(e.z, w2);
        BODY(e.w, w3);
    }
#undef BODY

    // layer-1 recurrence per element (np rounding order) -> s1 bitmasks
    u16 ob[4];
#pragma unroll
    for (int q = 0; q < 4; ++q) {
        float syn = 0.f, mem = 0.f;
        u32 obits = 0;
#pragma unroll
        for (int t = 0; t < 15; ++t) {
            float h1 = acc[t][q >> 1][q & 1];   // static indices after unroll
            float ns = __fadd_rn(__fmul_rn(0.9f, syn), h1);
            float nm = __fadd_rn(__fmul_rn(0.85f, mem), ns);
            bool sp = nm > 1.0f;
            obits |= (sp ? 1u : 0u) << t;
            syn = ns;
            mem = sp ? 0.f : nm;
        }
        ob[q] = (u16)obits;
    }
    uint2 pk;
    pk.x = (u32)ob[0] | ((u32)ob[1] << 16);
    pk.y = (u32)ob[2] | ((u32)ob[3] << 16);
    *(uint2*)(s1b + (size_t)row * 2048 + j0) = pk;
}

// ---- K3: out = tanh(sum_t s1_t @ W2) (order-free reduction) ----
__global__ __launch_bounds__(256) void out_kernel(
    const u16* __restrict__ s1b, const float* __restrict__ W2,
    float* __restrict__ out) {
    __shared__ float P[4][15][8];
    int row = blockIdx.x;
    int tid = threadIdx.x, lane = tid & 63, wv = tid >> 6;
    const u16* srow = s1b + (size_t)row * 2048;
    union { uint4 v; u16 m[8]; } u;
    u.v = *(const uint4*)(srow + tid * 8);
#pragma unroll
    for (int t = 0; t < 15; ++t) {
        float a[8];
#pragma unroll
        for (int jj = 0; jj < 8; ++jj) a[jj] = 0.f;
#pragma unroll
        for (int kk = 0; kk < 8; ++kk) {
            const float* wr = W2 + (size_t)(tid * 8 + kk) * 8;
            if ((u.m[kk] >> t) & 1u) {
#pragma unroll
                for (int jj = 0; jj < 8; ++jj)
                    a[jj] = __fadd_rn(a[jj], wr[jj]);
            }
        }
#pragma unroll
        for (int jj = 0; jj < 8; ++jj) {
            float v = a[jj];
#pragma unroll
            for (int m = 1; m < 64; m <<= 1) v += __shfl_xor(v, m, 64);
            a[jj] = v;
        }
        if (lane == 0) {
#pragma unroll
            for (int jj = 0; jj < 8; ++jj) P[wv][t][jj] = a[jj];
        }
    }
    __syncthreads();
    if (tid < 8) {
        float m2 = 0.f;
#pragma unroll
        for (int t = 0; t < 15; ++t) {
            float s = __fadd_rn(__fadd_rn(P[0][t][tid], P[1][t][tid]),
                                __fadd_rn(P[2][t][tid], P[3][t][tid]));
            m2 = __fadd_rn(m2, s);
        }
        out[(size_t)row * 8 + tid] = tanhf(m2);
    }
}

extern "C" void kernel_launch(void* const* d_in, const int* in_sizes, int n_in,
                              void* d_out, int out_size, void* d_ws, size_t ws_size,
                              hipStream_t stream) {
    const float* inp = (const float*)d_in[0];
    const float* W0  = (const float*)d_in[1];
    const float* W1  = (const float*)d_in[2];
    const float* W2  = (const float*)d_in[3];
    float* out = (float*)d_out;
    char* ws = (char*)d_ws;

    u16* s0bR = (u16*)(ws + 0);            // 16,777,216  [row][k] 15-bit masks
    u16* s1b  = (u16*)(ws + 16777216);     // 16,777,216  [row][j] 15-bit masks
    u32* list = (u32*)(ws + 33554432);     // 33,554,432  [row][2048] (k<<16|mask)
    int* ccnt = (int*)(ws + 67108864);     //     16,384  padded counts
    if (ws_size < 67125248) return;        // ~64 MB scratch

    h0_kernel<<<dim3(8, 128), 256, 0, stream>>>(inp, W0, s0bR);
    compact_kernel<<<1024, 256, 0, stream>>>(s0bR, list, ccnt);
    h1_fused8<<<8192, 256, 0, stream>>>(W1, list, ccnt, s1b);
    out_kernel<<<4096, 256, 0, stream>>>(s1b, W2, out);
}